// Round 11
// baseline (1039.544 us; speedup 1.0000x reference)
//
#include <hip/hip_runtime.h>
#include <math.h>

// Problem constants
#define NPTS 8192
#define MNODE 2048

// ---------------- ws layout (float element offsets) ----------------
#define WS_XT1  0L          // xt1_ [4][128][8192] (x1 ch0-63, x2 ch64-127) — live whole pass
#define WS_A    4194304L    // x34 [4][512][2048] (x3 ch0-255, x4 ch256-511); sort scratch EARLY
#define WS_B    8388608L    // scores [4][8][8192] early; s8 [4][128][8192] later
#define WS_C    12582912L   // h [4][256][2048] early; s6/s7 [4][128][2048] later
#define WS_D    14680064L   // sup [4][128][8192]; s9 later
#define WS_TOPV 18874368L   // [4][2048]
#define WS_TOPI 18882560L   // int [4][2048]
#define WS_NODE 18890752L   // [4][3][2048]
#define WS_MAXP 18915328L   // [4][1024]
#define WS_VEC  18919424L   // [4][2048]
#define WS_C1   18927616L   // [4][512]
#define WS_C2   18929664L   // [4][256]
#define WS_B6   18930688L   // [4][128]
#define WS_K20  18931200L   // int [4][2048][20]; ALSO convmax partial-max scratch (disjoint lifetime)
#define WS_K3I  19095040L   // int [4][8192][3]
#define WS_K3W  19193344L   // [4][8192][3]
// end = 19291648 floats = 73.6 MB

// ---------------- conv1: x[4,3,8192] -> xt1_ ch0-63 ----------------
__global__ __launch_bounds__(256) void k_conv1(const float* __restrict__ x,
                                               const float* __restrict__ W,
                                               const float* __restrict__ sc,
                                               const float* __restrict__ bi,
                                               float* __restrict__ out) {
    int t = blockIdx.x * 256 + threadIdx.x;           // 4*64*8192
    int n = t & 8191, o = (t >> 13) & 63, b = t >> 19;
    const float* xb = x + (long)b * 3 * NPTS;
    float a = W[o * 3 + 0] * xb[n] + W[o * 3 + 1] * xb[NPTS + n] + W[o * 3 + 2] * xb[2 * NPTS + n];
    a = fmaxf(a * sc[o] + bi[o], 0.f);
    out[((long)b * 128 + o) * NPTS + n] = a;
}

// ---------------- conv2: xt1_ ch0-63 -> xt1_ ch64-127 ----------------
__global__ __launch_bounds__(256) void k_conv2(const float* __restrict__ in,
                                               const float* __restrict__ W,
                                               const float* __restrict__ sc,
                                               const float* __restrict__ bi,
                                               float* __restrict__ out) {
    int t = blockIdx.x * 256 + threadIdx.x;
    int n = t & 8191, o = (t >> 13) & 63, b = t >> 19;
    const float* ip = in + (long)b * 128 * NPTS + n;
    const float* wp = W + o * 64;
    float a = 0.f;
#pragma unroll 8
    for (int c = 0; c < 64; ++c) a = fmaf(wp[c], ip[(long)c * NPTS], a);
    out[((long)b * 128 + 64 + o) * NPTS + n] = fmaxf(a * sc[o] + bi[o], 0.f);
}

// 16-output-tile FMA block: reads 4x float4 broadcast from Wl at row c16, FMAs into acc[16]
#define CMAX_FMA16()                                                        \
    {                                                                       \
        const float4* wp4 = reinterpret_cast<const float4*>(Wl + c16);      \
        _Pragma("unroll")                                                   \
        for (int g = 0; g < 4; ++g) {                                       \
            float4 w = wp4[g];                                              \
            acc[4 * g + 0].x = fmaf(w.x, v.x, acc[4 * g + 0].x);            \
            acc[4 * g + 0].y = fmaf(w.x, v.y, acc[4 * g + 0].y);            \
            acc[4 * g + 0].z = fmaf(w.x, v.z, acc[4 * g + 0].z);            \
            acc[4 * g + 0].w = fmaf(w.x, v.w, acc[4 * g + 0].w);            \
            acc[4 * g + 1].x = fmaf(w.y, v.x, acc[4 * g + 1].x);            \
            acc[4 * g + 1].y = fmaf(w.y, v.y, acc[4 * g + 1].y);            \
            acc[4 * g + 1].z = fmaf(w.y, v.z, acc[4 * g + 1].z);            \
            acc[4 * g + 1].w = fmaf(w.y, v.w, acc[4 * g + 1].w);            \
            acc[4 * g + 2].x = fmaf(w.z, v.x, acc[4 * g + 2].x);            \
            acc[4 * g + 2].y = fmaf(w.z, v.y, acc[4 * g + 2].y);            \
            acc[4 * g + 2].z = fmaf(w.z, v.z, acc[4 * g + 2].z);            \
            acc[4 * g + 2].w = fmaf(w.z, v.w, acc[4 * g + 2].w);            \
            acc[4 * g + 3].x = fmaf(w.w, v.x, acc[4 * g + 3].x);            \
            acc[4 * g + 3].y = fmaf(w.w, v.y, acc[4 * g + 3].y);            \
            acc[4 * g + 3].z = fmaf(w.w, v.z, acc[4 * g + 3].z);            \
            acc[4 * g + 3].w = fmaf(w.w, v.w, acc[4 * g + 3].w);            \
        }                                                                   \
    }

// ---------------- fused conv(+cbias)(+bn)(+relu) + partial max, DUAL param set ----------------
// 16-wide O-tile, Wl transposed [C][16], c-loop UNROLLED x2 (C even) with 2 loads in flight.
// Parallel epilogue (one tree for all 16 o). pmax finalized by k_maxred (max assoc).
__global__ __launch_bounds__(256) void k_convmax(
        const float* __restrict__ in, int C, long ibs,
        const float* __restrict__ W1, const float* __restrict__ cb1,
        const float* __restrict__ sc1, const float* __restrict__ bi1, int relu1,
        float* __restrict__ pmax1,
        const float* __restrict__ W2, const float* __restrict__ cb2,
        const float* __restrict__ sc2, const float* __restrict__ bi2, int relu2,
        float* __restrict__ pmax2,
        int wpitch, int O, int Nn) {
    extern __shared__ float sm_[];
    float* Wl = sm_;              // [C][16]
    float* red = sm_ + 16 * C;    // [16][257] padded rows
    int b = blockIdx.z;
    int ns = blockIdx.x;
    int oblocks = O >> 4;
    int setid = (int)blockIdx.y / oblocks;          // uniform per block
    int og0 = ((int)blockIdx.y - setid * oblocks) * 16;
    const float* W  = setid ? W2 : W1;
    const float* cb = setid ? cb2 : cb1;
    const float* sc = setid ? sc2 : sc1;
    const float* bi = setid ? bi2 : bi1;
    int do_relu     = setid ? relu2 : relu1;
    float* pmax     = setid ? pmax2 : pmax1;
    for (int t = threadIdx.x; t < 16 * C; t += 256) {
        int c = t >> 4, o = t & 15;
        Wl[t] = W[(long)(og0 + o) * wpitch + c];
    }
    __syncthreads();
    int n0 = ns * 1024 + threadIdx.x * 4;
    float4 acc[16];
#pragma unroll
    for (int o = 0; o < 16; ++o) acc[o] = make_float4(0.f, 0.f, 0.f, 0.f);
    const float* p = in + (long)b * ibs + n0;
    float4 v0 = *reinterpret_cast<const float4*>(p);
    float4 v1 = *reinterpret_cast<const float4*>(p + Nn);
    int c = 0;
    for (; c + 2 < C; c += 2) {
        float4 n2 = *reinterpret_cast<const float4*>(p + (long)(c + 2) * Nn);
        float4 n3 = *reinterpret_cast<const float4*>(p + (long)(c + 3) * Nn);
        { int c16 = c * 16; float4 v = v0; CMAX_FMA16(); }
        { int c16 = (c + 1) * 16; float4 v = v1; CMAX_FMA16(); }
        v0 = n2; v1 = n3;
    }
    { int c16 = (C - 2) * 16; float4 v = v0; CMAX_FMA16(); }
    { int c16 = (C - 1) * 16; float4 v = v1; CMAX_FMA16(); }
    // epilogue: bn/relu + horizontal max4, stage ALL 16 rows, single parallel tree
#pragma unroll
    for (int o = 0; o < 16; ++o) {
        float cbv = cb ? cb[og0 + o] : 0.f;
        float scv = sc ? sc[og0 + o] : 1.f;
        float biv = bi ? bi[og0 + o] : 0.f;
        float4 a = acc[o];
        float vx = (a.x + cbv) * scv + biv;
        float vy = (a.y + cbv) * scv + biv;
        float vz = (a.z + cbv) * scv + biv;
        float vw = (a.w + cbv) * scv + biv;
        if (do_relu) {
            vx = fmaxf(vx, 0.f); vy = fmaxf(vy, 0.f);
            vz = fmaxf(vz, 0.f); vw = fmaxf(vw, 0.f);
        }
        red[o * 257 + threadIdx.x] = fmaxf(fmaxf(vx, vy), fmaxf(vz, vw));
    }
    __syncthreads();
    for (int ls = 7; ls >= 0; --ls) {
        int s = 1 << ls;
        for (int w = threadIdx.x; w < 16 * s; w += 256) {
            int o = w >> ls, i = w & (s - 1);
            float* r = red + o * 257;
            r[i] = fmaxf(r[i], r[i + s]);
        }
        __syncthreads();
    }
    if (threadIdx.x < 16)
        pmax[((long)ns * 4 + b) * O + og0 + threadIdx.x] = red[threadIdx.x * 257];
}

// finalize: out[b*obs + o] = max over nsplit partials
__global__ __launch_bounds__(256) void k_maxred(const float* __restrict__ pmax, int nsplit,
                                                int O, float* __restrict__ out, long obs) {
    int t = blockIdx.x * 256 + threadIdx.x;
    if (t >= 4 * O) return;
    int o = t % O, b = t / O;
    float m = -3.0e38f;
    for (int s = 0; s < nsplit; ++s) m = fmaxf(m, pmax[((long)s * 4 + b) * O + o]);
    out[(long)b * obs + o] = m;
}

// ---------------- generic conv(+extra)(+bn)(+relu), up to 2 concat inputs ----------------
// block 256, grid (Nn/1024, ceil(O/16), B). 16-wide O-tile (convmax-proven shape),
// Wl transposed [Ct][16] zero-padded for o>=on, 1-deep input prefetch.
__global__ __launch_bounds__(256) void k_conv(const float* __restrict__ in1, int C1, long ibs1,
                                              const float* __restrict__ in2, int C2, long ibs2,
                                              const float* __restrict__ W, int wpitch,
                                              const float* __restrict__ extra,
                                              const float* __restrict__ sc,
                                              const float* __restrict__ bi, int do_relu,
                                              float* __restrict__ out, long obs, int O, int Nn) {
    __shared__ float Wl[384 * 16];
    int b = blockIdx.z;
    int og0 = blockIdx.y * 16;
    int on = O - og0; if (on > 16) on = 16;
    int Ct = C1 + C2;
    for (int t = threadIdx.x; t < Ct * 16; t += 256) {
        int c = t >> 4, o = t & 15;
        Wl[t] = (o < on) ? W[(long)(og0 + o) * wpitch + c] : 0.f;
    }
    __syncthreads();
    int n0 = blockIdx.x * 1024 + threadIdx.x * 4;
    float4 acc[16];
#pragma unroll
    for (int o = 0; o < 16; ++o) acc[o] = make_float4(0.f, 0.f, 0.f, 0.f);
    const float* p1 = in1 + (long)b * ibs1 + n0;
    {
        float4 v = *reinterpret_cast<const float4*>(p1);
        for (int c = 0; c < C1 - 1; ++c) {
            float4 vn = *reinterpret_cast<const float4*>(p1 + (long)(c + 1) * Nn);
            int c16 = c * 16;
            CMAX_FMA16();
            v = vn;
        }
        int c16 = (C1 - 1) * 16;
        CMAX_FMA16();
    }
    if (in2) {
        const float* p2 = in2 + (long)b * ibs2 + n0;
        float4 v = *reinterpret_cast<const float4*>(p2);
        for (int c = 0; c < C2 - 1; ++c) {
            float4 vn = *reinterpret_cast<const float4*>(p2 + (long)(c + 1) * Nn);
            int c16 = (C1 + c) * 16;
            CMAX_FMA16();
            v = vn;
        }
        int c16 = (Ct - 1) * 16;
        CMAX_FMA16();
    }
#pragma unroll
    for (int o = 0; o < 16; ++o) {
        if (o < on) {
            float e = extra ? extra[(long)b * O + og0 + o] : 0.f;
            float s = sc ? sc[og0 + o] : 1.f;
            float bv = bi ? bi[og0 + o] : 0.f;
            float4 a = acc[o];
            a.x = (a.x + e) * s + bv;
            a.y = (a.y + e) * s + bv;
            a.z = (a.z + e) * s + bv;
            a.w = (a.w + e) * s + bv;
            if (do_relu) {
                a.x = fmaxf(a.x, 0.f); a.y = fmaxf(a.y, 0.f);
                a.z = fmaxf(a.z, 0.f); a.w = fmaxf(a.w, 0.f);
            }
            *reinterpret_cast<float4*>(out + (long)b * obs + (long)(og0 + o) * Nn + n0) = a;
        }
    }
}

// ---------------- scores[b][e][n] = sigmoid(sum_c feat*vec), one e per block ----------------
// grid (NPTS/1024, 8, 4): 256 blocks (was 32 — latency-starved).
__global__ __launch_bounds__(256) void k_scores(const float* __restrict__ feat,
                                                const float* __restrict__ maxp,
                                                float* __restrict__ scores) {
    __shared__ float wl[128];
    int b = blockIdx.z, e = blockIdx.y;
    if (threadIdx.x < 128) wl[threadIdx.x] = maxp[b * 1024 + threadIdx.x * 8 + e];
    __syncthreads();
    int n0 = blockIdx.x * 1024 + threadIdx.x * 4;
    float4 acc = make_float4(0.f, 0.f, 0.f, 0.f);
    const float* p = feat + (long)b * 128 * NPTS + n0;
    float4 v = *reinterpret_cast<const float4*>(p);
    for (int c = 0; c < 127; ++c) {
        float4 vn = *reinterpret_cast<const float4*>(p + (long)(c + 1) * NPTS);
        float w = wl[c];
        acc.x = fmaf(w, v.x, acc.x);
        acc.y = fmaf(w, v.y, acc.y);
        acc.z = fmaf(w, v.z, acc.z);
        acc.w = fmaf(w, v.w, acc.w);
        v = vn;
    }
    {
        float w = wl[127];
        acc.x = fmaf(w, v.x, acc.x);
        acc.y = fmaf(w, v.y, acc.y);
        acc.z = fmaf(w, v.z, acc.z);
        acc.w = fmaf(w, v.w, acc.w);
    }
    acc.x = 1.f / (1.f + expf(-acc.x));
    acc.y = 1.f / (1.f + expf(-acc.y));
    acc.z = 1.f / (1.f + expf(-acc.z));
    acc.w = 1.f / (1.f + expf(-acc.w));
    *reinterpret_cast<float4*>(scores + ((long)b * 8 + e) * NPTS + n0) = acc;
}

// ---------------- hierarchical exact sorted top-256 per (b,e) ----------------
__global__ __launch_bounds__(256) void k_sorta(const float* __restrict__ scores,
                                               unsigned int* __restrict__ kout,
                                               unsigned short* __restrict__ iout) {
    __shared__ unsigned int kv[1024];
    __shared__ unsigned short ki[1024];
    int ch = blockIdx.x & 7;
    const float* sp = scores + (long)(blockIdx.x >> 3) * NPTS + ch * 1024;
    for (int t = threadIdx.x; t < 1024; t += 256) {
        kv[t] = __float_as_uint(sp[t]) ^ 0xFFFFFFFFu;
        ki[t] = (unsigned short)(ch * 1024 + t);
    }
    __syncthreads();
    for (int k = 2; k <= 1024; k <<= 1) {
        for (int j = k >> 1; j > 0; j >>= 1) {
            for (int t = threadIdx.x; t < 1024; t += 256) {
                int ixj = t ^ j;
                if (ixj > t) {
                    unsigned int va = kv[t], vb = kv[ixj];
                    unsigned short ia = ki[t], ib = ki[ixj];
                    bool up = ((t & k) == 0);
                    bool gt = (va > vb) || (va == vb && ia > ib);
                    if (gt == up) { kv[t] = vb; kv[ixj] = va; ki[t] = ib; ki[ixj] = ia; }
                }
            }
            __syncthreads();
        }
    }
    if (threadIdx.x < 256) {
        kout[blockIdx.x * 256 + threadIdx.x] = kv[threadIdx.x];
        iout[blockIdx.x * 256 + threadIdx.x] = ki[threadIdx.x];
    }
}

__global__ __launch_bounds__(512) void k_sortb(const unsigned int* __restrict__ kin,
                                               const unsigned short* __restrict__ iin,
                                               float* __restrict__ topv,
                                               int* __restrict__ topi) {
    __shared__ unsigned int kv[2048];
    __shared__ unsigned short ki[2048];
    int be = blockIdx.x, b = be >> 3, e = be & 7;
    for (int t = threadIdx.x; t < 2048; t += 512) {
        kv[t] = kin[be * 2048 + t];
        ki[t] = iin[be * 2048 + t];
    }
    __syncthreads();
    for (int k = 2; k <= 2048; k <<= 1) {
        for (int j = k >> 1; j > 0; j >>= 1) {
            for (int t = threadIdx.x; t < 2048; t += 512) {
                int ixj = t ^ j;
                if (ixj > t) {
                    unsigned int va = kv[t], vb = kv[ixj];
                    unsigned short ia = ki[t], ib = ki[ixj];
                    bool up = ((t & k) == 0);
                    bool gt = (va > vb) || (va == vb && ia > ib);
                    if (gt == up) { kv[t] = vb; kv[ixj] = va; ki[t] = ib; ki[ixj] = ia; }
                }
            }
            __syncthreads();
        }
    }
    for (int r = threadIdx.x; r < 256; r += 512) {
        int j = r * 8 + e;  // torch-order reshape: values[b, r*8+e] = v[b,e,r]
        topv[b * 2048 + j] = __uint_as_float(kv[r] ^ 0xFFFFFFFFu);
        topi[b * 2048 + j] = (int)ki[r];
    }
}

// ---------------- pool gather: node, node_static (coords) ----------------
__global__ __launch_bounds__(256) void k_poolgather(const float* __restrict__ xyz,
                                                    const float* __restrict__ topv,
                                                    const int* __restrict__ topi,
                                                    float* __restrict__ node_ws,
                                                    float* __restrict__ out_node,
                                                    float* __restrict__ out_nstat) {
    int t = blockIdx.x * 256 + threadIdx.x;  // 4*2048
    int j = t & 2047, b = t >> 11;
    int i = topi[b * 2048 + j];
    float v = topv[b * 2048 + j];
#pragma unroll
    for (int k = 0; k < 3; ++k) {
        float sx = xyz[((long)b * 3 + k) * NPTS + i];
        float nd = sx * v;
        out_nstat[((long)b * 3 + k) * MNODE + j] = sx;
        out_node[((long)b * 3 + k) * MNODE + j] = nd;
        node_ws[((long)b * 3 + k) * MNODE + j] = nd;
    }
}

// ---------------- nf1: h ch0-127 = feat gathered * values ----------------
__global__ __launch_bounds__(256) void k_nf1(const float* __restrict__ feat,
                                             const float* __restrict__ topv,
                                             const int* __restrict__ topi,
                                             float* __restrict__ h) {
    int t = blockIdx.x * 256 + threadIdx.x;  // 4*128*2048
    int j = t & 2047, c = (t >> 11) & 127, b = t >> 18;
    int i = topi[b * 2048 + j];
    float v = topv[b * 2048 + j];
    h[((long)b * 256 + c) * MNODE + j] = feat[((long)b * 128 + c) * NPTS + i] * v;
}

// ---------------- knn20 (block-per-node): exact stable top-20 ----------------
__device__ __forceinline__ unsigned int fsortbits(float f) {
    unsigned int u = __float_as_uint(f);
    return u ^ ((unsigned int)((int)u >> 31) | 0x80000000u);
}

__global__ __launch_bounds__(256) void k_knn20(const float* __restrict__ xyz,
                                               const float* __restrict__ node,
                                               int* __restrict__ k20) {
    __shared__ unsigned int s1[256];
    __shared__ int s2[256];
    __shared__ int lcnt;
    int m = blockIdx.x & 2047, b = blockIdx.x >> 11;
    int t = threadIdx.x;
    float nx = node[((long)b * 3 + 0) * MNODE + m];
    float ny = node[((long)b * 3 + 1) * MNODE + m];
    float nz = node[((long)b * 3 + 2) * MNODE + m];
    float sm = nx * nx + ny * ny + nz * nz;
    const float* xb = xyz + (long)b * 3 * NPTS;
    unsigned int kmin = 0xFFFFFFFFu;
    for (int i = 0; i < 32; ++i) {
        int n = i * 256 + t;
        float px = xb[n], py = xb[NPTS + n], pz = xb[2 * NPTS + n];
        float d = (px * px + py * py + pz * pz) + sm - 2.f * (px * nx + py * ny + pz * nz);
        unsigned int key = fsortbits(d);
        kmin = key < kmin ? key : kmin;
    }
    s1[t] = kmin;
    if (t == 0) lcnt = 0;
    __syncthreads();
    for (int k = 2; k <= 256; k <<= 1) {
        for (int j = k >> 1; j > 0; j >>= 1) {
            int ixj = t ^ j;
            if (ixj > t) {
                unsigned int va = s1[t], vb = s1[ixj];
                bool up = ((t & k) == 0);
                if ((va > vb) == up) { s1[t] = vb; s1[ixj] = va; }
            }
            __syncthreads();
        }
    }
    unsigned int keyT = s1[19];
    __syncthreads();
    for (int i = 0; i < 32; ++i) {
        int n = i * 256 + t;
        float px = xb[n], py = xb[NPTS + n], pz = xb[2 * NPTS + n];
        float d = (px * px + py * py + pz * pz) + sm - 2.f * (px * nx + py * ny + pz * nz);
        unsigned int key = fsortbits(d);
        if (key <= keyT) {
            int p = atomicAdd(&lcnt, 1);
            if (p < 128) { s1[p] = key; s2[p] = n; }
        }
    }
    __syncthreads();
    int cnt = lcnt;  // uniform across block
    if (cnt <= 128) {
        if (t >= cnt && t < 128) { s1[t] = 0xFFFFFFFFu; s2[t] = 0x7FFFFFFF; }
        __syncthreads();
        for (int k = 2; k <= 128; k <<= 1) {
            for (int j = k >> 1; j > 0; j >>= 1) {
                if (t < 128) {
                    int ixj = t ^ j;
                    if (ixj > t) {
                        unsigned int va = s1[t], vb = s1[ixj];
                        int ia = s2[t], ib = s2[ixj];
                        bool up = ((t & k) == 0);
                        bool gt = (va > vb) || (va == vb && ia > ib);
                        if (gt == up) { s1[t] = vb; s1[ixj] = va; s2[t] = ib; s2[ixj] = ia; }
                    }
                }
                __syncthreads();
            }
        }
        if (t < 20) k20[((long)b * 2048 + m) * 20 + t] = s2[t];
    } else {
        unsigned int lastk = 0u; int lasti = -1;
        for (int r = 0; r < 20; ++r) {
            unsigned int bk = 0xFFFFFFFFu; int bi = 0x7FFFFFFF;
            for (int i = 0; i < 32; ++i) {
                int n = i * 256 + t;
                float px = xb[n], py = xb[NPTS + n], pz = xb[2 * NPTS + n];
                float d = (px * px + py * py + pz * pz) + sm - 2.f * (px * nx + py * ny + pz * nz);
                unsigned int key = fsortbits(d);
                bool gtlast = (key > lastk) || (key == lastk && n > lasti);
                bool ltbest = (key < bk) || (key == bk && n < bi);
                if (gtlast && ltbest) { bk = key; bi = n; }
            }
            s1[t] = bk; s2[t] = bi;
            __syncthreads();
            for (int s = 128; s > 0; s >>= 1) {
                if (t < s) {
                    unsigned int vo = s1[t + s]; int io = s2[t + s];
                    unsigned int vm = s1[t]; int im = s2[t];
                    if (vo < vm || (vo == vm && io < im)) { s1[t] = vo; s2[t] = io; }
                }
                __syncthreads();
            }
            if (t == 0) k20[((long)b * 2048 + m) * 20 + r] = s2[0];
            lastk = s1[0]; lasti = s2[0];
            __syncthreads();
        }
    }
}

// ---------------- aggregate: h ch128-255 = max over 20 gathered feats ----------------
__global__ __launch_bounds__(256) void k_agg(const float* __restrict__ feat,
                                             const int* __restrict__ k20,
                                             float* __restrict__ h) {
    int t = blockIdx.x * 256 + threadIdx.x;  // 4*128*2048
    int m = t & 2047, c = (t >> 11) & 127, b = t >> 18;
    const int* ip = k20 + ((long)b * 2048 + m) * 20;
    const float* fb = feat + ((long)b * 128 + c) * NPTS;
    float mx = -3.0e38f;
#pragma unroll
    for (int q = 0; q < 20; ++q) mx = fmaxf(mx, fb[ip[q] & 8191]);  // mask = fault isolation
    h[((long)b * 256 + 128 + c) * MNODE + m] = mx;
}

// ---------------- gemv: block per output o, all 4 batches; coalesced row read ----------------
__global__ __launch_bounds__(256) void k_gemv(const float* __restrict__ in, int C,
                                              const float* __restrict__ W, int wpitch,
                                              const float* __restrict__ lb,
                                              const float* __restrict__ sc,
                                              const float* __restrict__ bi, int do_relu,
                                              float* __restrict__ out, int O) {
    __shared__ float red[256];
    int o = blockIdx.x;
    int t = threadIdx.x;
    const float* wp = W + (long)o * wpitch;
    float a0 = 0.f, a1 = 0.f, a2 = 0.f, a3 = 0.f;
    for (int c = t * 4; c < C; c += 1024) {
        float4 w = *reinterpret_cast<const float4*>(wp + c);
        float4 v0 = *reinterpret_cast<const float4*>(in + 0L * C + c);
        float4 v1 = *reinterpret_cast<const float4*>(in + 1L * C + c);
        float4 v2 = *reinterpret_cast<const float4*>(in + 2L * C + c);
        float4 v3 = *reinterpret_cast<const float4*>(in + 3L * C + c);
        a0 += w.x * v0.x + w.y * v0.y + w.z * v0.z + w.w * v0.w;
        a1 += w.x * v1.x + w.y * v1.y + w.z * v1.z + w.w * v1.w;
        a2 += w.x * v2.x + w.y * v2.y + w.z * v2.z + w.w * v2.w;
        a3 += w.x * v3.x + w.y * v3.y + w.z * v3.z + w.w * v3.w;
    }
    float lbv = lb ? lb[o] : 0.f;
    float scv = sc ? sc[o] : 1.f;
    float biv = bi ? bi[o] : 0.f;
#pragma unroll
    for (int b = 0; b < 4; ++b) {
        float a = (b == 0) ? a0 : (b == 1) ? a1 : (b == 2) ? a2 : a3;
        __syncthreads();
        red[t] = a;
        __syncthreads();
        for (int s2 = 128; s2 > 0; s2 >>= 1) {
            if (t < s2) red[t] += red[t + s2];
            __syncthreads();
        }
        if (t == 0) {
            float r = (red[0] + lbv) * scv + biv;
            if (do_relu) r = fmaxf(r, 0.f);
            out[(long)b * O + o] = r;
        }
    }
}

// ---------------- unpool knn3: block = 32 points x 8 threads/point, nodes staged in LDS ----
__global__ __launch_bounds__(256) void k_knn3(const float* __restrict__ xyz,
                                              const float* __restrict__ node,
                                              int* __restrict__ k3i, float* __restrict__ k3w) {
    __shared__ float sx[2048], sy[2048], sz[2048], sn[2048];
    __shared__ float md[256][3];
    __shared__ int   mi[256][3];
    int b = blockIdx.x >> 8;                 // 256 blocks per batch
    int pbase = (blockIdx.x & 255) * 32;
    int t = threadIdx.x;
    const float* nb = node + (long)b * 3 * MNODE;
    for (int j = t; j < 2048; j += 256) {
        float qx = nb[j], qy = nb[MNODE + j], qz = nb[2 * MNODE + j];
        sx[j] = qx; sy[j] = qy; sz[j] = qz;
        sn[j] = qx * qx + qy * qy + qz * qz;   // reference computes |b|^2 once per node
    }
    __syncthreads();
    int i = t & 31, q = t >> 5;
    int n = pbase + i;
    float px = xyz[((long)b * 3 + 0) * NPTS + n];
    float py = xyz[((long)b * 3 + 1) * NPTS + n];
    float pz = xyz[((long)b * 3 + 2) * NPTS + n];
    float sp = px * px + py * py + pz * pz;
    float d0 = 3.0e38f, d1 = 3.0e38f, d2 = 3.0e38f;
    int i0 = 0, i1 = 0, i2 = 0;
    int m0 = q * 256;
#pragma unroll 4
    for (int k = 0; k < 256; ++k) {
        int m = m0 + k;
        float d = (sp + sn[m]) - 2.f * (px * sx[m] + py * sy[m] + pz * sz[m]);
        if (d < d2) {
            d2 = d; i2 = m;
            if (d2 < d1) { float td = d1; d1 = d2; d2 = td; int ti = i1; i1 = i2; i2 = ti; }
            if (d1 < d0) { float td = d0; d0 = d1; d1 = td; int ti = i0; i0 = i1; i1 = ti; }
        }
    }
    md[t][0] = d0; md[t][1] = d1; md[t][2] = d2;
    mi[t][0] = i0; mi[t][1] = i1; mi[t][2] = i2;
    __syncthreads();
    if (t < 32) {
        int p0 = 0, p1 = 0, p2 = 0, p3 = 0, p4 = 0, p5 = 0, p6 = 0, p7 = 0;
        float rd[3]; int ri[3];
#pragma unroll
        for (int r = 0; r < 3; ++r) {
            float bestd = 3.0e38f; int besti = 0x7FFFFFFF; int bestq = -1;
#define KNN3_HEAD(QQ, PV)                                                              \
            {                                                                          \
                float dd = md[(QQ) * 32 + t][PV]; int ii = mi[(QQ) * 32 + t][PV];      \
                if (dd < bestd || (dd == bestd && ii < besti)) {                       \
                    bestd = dd; besti = ii; bestq = (QQ);                              \
                }                                                                      \
            }
            KNN3_HEAD(0, p0) KNN3_HEAD(1, p1) KNN3_HEAD(2, p2) KNN3_HEAD(3, p3)
            KNN3_HEAD(4, p4) KNN3_HEAD(5, p5) KNN3_HEAD(6, p6) KNN3_HEAD(7, p7)
#undef KNN3_HEAD
            rd[r] = bestd; ri[r] = besti;
            p0 += (bestq == 0); p1 += (bestq == 1); p2 += (bestq == 2); p3 += (bestq == 3);
            p4 += (bestq == 4); p5 += (bestq == 5); p6 += (bestq == 6); p7 += (bestq == 7);
        }
        // reference: w = softmax(-negd) = softmax over the squared distances themselves
        float mxd = fmaxf(rd[0], fmaxf(rd[1], rd[2]));
        float e0 = expf(rd[0] - mxd), e1 = expf(rd[1] - mxd), e2 = expf(rd[2] - mxd);
        float inv = 1.f / (e0 + e1 + e2);
        long base = ((long)b * NPTS + pbase + t) * 3;
        k3i[base] = ri[0]; k3i[base + 1] = ri[1]; k3i[base + 2] = ri[2];
        k3w[base] = e0 * inv; k3w[base + 1] = e1 * inv; k3w[base + 2] = e2 * inv;
    }
}

__global__ __launch_bounds__(256) void k_unpool(const float* __restrict__ s7,
                                                const int* __restrict__ k3i,
                                                const float* __restrict__ k3w,
                                                float* __restrict__ sup) {
    int t = blockIdx.x * 256 + threadIdx.x;  // 4*128*8192
    int n = t & 8191, c = (t >> 13) & 127, b = t >> 20;
    long base = ((long)b * NPTS + n) * 3;
    const float* spp = s7 + ((long)b * 128 + c) * MNODE;
    float a = k3w[base] * spp[k3i[base]] + k3w[base + 1] * spp[k3i[base + 1]] +
              k3w[base + 2] * spp[k3i[base + 2]];
    sup[((long)b * 128 + c) * NPTS + n] = a;
}

extern "C" void kernel_launch(void* const* d_in, const int* in_sizes, int n_in,
                              void* d_out, int out_size, void* d_ws, size_t ws_size,
                              hipStream_t stream) {
    const float* x     = (const float*)d_in[0];
    const float* c1w   = (const float*)d_in[1];
    const float* c2w   = (const float*)d_in[2];
    const float* c2mw  = (const float*)d_in[3];
    const float* c3w   = (const float*)d_in[4];
    const float* c4w   = (const float*)d_in[5];
    const float* c5w   = (const float*)d_in[6];
    const float* c6w   = (const float*)d_in[7];
    const float* c7w   = (const float*)d_in[8];
    const float* c8w   = (const float*)d_in[9];
    const float* c9w   = (const float*)d_in[10];
    const float* c10w  = (const float*)d_in[11];
    const float* bn1s  = (const float*)d_in[12]; const float* bn1b  = (const float*)d_in[13];
    const float* bn2s  = (const float*)d_in[14]; const float* bn2b  = (const float*)d_in[15];
    const float* bn2ms = (const float*)d_in[16]; const float* bn2mb = (const float*)d_in[17];
    const float* bn3s  = (const float*)d_in[18]; const float* bn3b  = (const float*)d_in[19];
    const float* bn4s  = (const float*)d_in[20]; const float* bn4b  = (const float*)d_in[21];
    const float* bn5s  = (const float*)d_in[22]; const float* bn5b  = (const float*)d_in[23];
    const float* bn6cs = (const float*)d_in[24]; const float* bn6cb = (const float*)d_in[25];
    const float* bn7cs = (const float*)d_in[26]; const float* bn7cb = (const float*)d_in[27];
    const float* bn8s  = (const float*)d_in[28]; const float* bn8b  = (const float*)d_in[29];
    const float* bn9s  = (const float*)d_in[30]; const float* bn9b  = (const float*)d_in[31];
    const float* bn6hs = (const float*)d_in[32]; const float* bn6hb = (const float*)d_in[33];
    const float* bn7hs = (const float*)d_in[34]; const float* bn7hb = (const float*)d_in[35];
    const float* poolw = (const float*)d_in[36]; const float* poolb = (const float*)d_in[37];
    const float* l1w   = (const float*)d_in[38];
    const float* l2w   = (const float*)d_in[39]; const float* l2b   = (const float*)d_in[40];
    const float* l3w   = (const float*)d_in[41]; const float* l3b   = (const float*)d_in[42];

    float* ws   = (float*)d_ws;
    float* xt1  = ws + WS_XT1;
    float* x34  = ws + WS_A;
    float* scor = ws + WS_B;
    float* s8   = ws + WS_B;                 // aliases scores (dead by then)
    float* hbuf = ws + WS_C;
    float* s6   = ws + WS_C;                 // aliases h (dead after conv3)
    float* s7   = ws + WS_C + 1048576L;
    float* sup  = ws + WS_D;
    float* s9   = ws + WS_D;                 // aliases sup (dead after conv8)
    float* topv = ws + WS_TOPV;
    int*   topi = (int*)(ws + WS_TOPI);
    float* node = ws + WS_NODE;
    float* maxp = ws + WS_MAXP;
    float* vec  = ws + WS_VEC;
    float* c1b  = ws + WS_C1;
    float* c2b_ = ws + WS_C2;
    float* b6   = ws + WS_B6;
    int*   k20  = (int*)(ws + WS_K20);
    float* pmax1 = ws + WS_K20;              // convmax partial scratch (k20 lifetime-disjoint)
    float* pmax2 = ws + WS_K20 + 32768;      // second set (8 splits * 4 * 1024)
    int*   k3i  = (int*)(ws + WS_K3I);
    float* k3w  = ws + WS_K3W;
    // sort scratch aliases x34 region (dead until conv3)
    unsigned int*   sskeys = (unsigned int*)(ws + WS_A);
    unsigned short* ssidx  = (unsigned short*)(ws + WS_A + 65536);

    float* out       = (float*)d_out;
    float* out_cls   = out;                  // [4,15]
    float* out_seg   = out + 60;             // [4,2,8192]
    float* out_node  = out + 60 + 65536;     // [4,3,2048]
    float* out_nstat = out_node + 24576;     // [4,3,2048]

    // x1, x2 -> xt1_
    k_conv1<<<dim3(8192), dim3(256), 0, stream>>>(x, c1w, bn1s, bn1b, xt1);
    k_conv2<<<dim3(8192), dim3(256), 0, stream>>>(xt1, c2w, bn2s, bn2b, xt1);
    // FUSED conv2m + pool-proj (both C=128, O=1024, same input): one launch, 2 param sets
    k_convmax<<<dim3(8, 128, 4), dim3(256), (16 * 128 + 16 * 257) * 4, stream>>>(
        xt1, 128, 128L * NPTS,
        c2mw, nullptr, bn2ms, bn2mb, 1, pmax1,
        poolw, poolb, nullptr, nullptr, 0, pmax2,
        128, 1024, NPTS);
    k_maxred<<<dim3(16), dim3(256), 0, stream>>>(pmax1, 8, 1024, vec, 2048);
    k_maxred<<<dim3(16), dim3(256), 0, stream>>>(pmax2, 8, 1024, maxp, 1024);
    // scores (one e per block: 256 blocks)
    k_scores<<<dim3(8, 8, 4), dim3(256), 0, stream>>>(xt1, maxp, scor);
    // exact top-256 per (b,e): hierarchical chunk-sort + merge-sort
    k_sorta<<<dim3(256), dim3(256), 0, stream>>>(scor, sskeys, ssidx);
    k_sortb<<<dim3(32), dim3(512), 0, stream>>>(sskeys, ssidx, topv, topi);
    // node / node_static / nf1
    k_poolgather<<<dim3(32), dim3(256), 0, stream>>>(x, topv, topi, node, out_node, out_nstat);
    k_nf1<<<dim3(4096), dim3(256), 0, stream>>>(xt1, topv, topi, hbuf);
    // aggregate (knn20 block-per-node + gather-max)
    k_knn20<<<dim3(8192), dim3(256), 0, stream>>>(x, node, k20);
    k_agg<<<dim3(4096), dim3(256), 0, stream>>>(xt1, k20, hbuf);
    // conv3 / conv4 -> x34 (16-wide o-tile)
    k_conv<<<dim3(2, 16, 4), dim3(256), 0, stream>>>(hbuf, 256, 256L * MNODE, nullptr, 0, 0,
                                                     c3w, 256, nullptr, bn3s, bn3b, 1,
                                                     x34, 512L * MNODE, 256, MNODE);
    k_conv<<<dim3(2, 16, 4), dim3(256), 0, stream>>>(x34, 256, 512L * MNODE, nullptr, 0, 0,
                                                     c4w, 256, nullptr, bn4s, bn4b, 1,
                                                     x34 + 256L * MNODE, 512L * MNODE, 256, MNODE);
    // conv5 fused max -> vector[:,1024:2048]  (k20 dead after k_agg -> pmax reuse safe)
    k_convmax<<<dim3(2, 64, 4), dim3(256), (16 * 512 + 16 * 257) * 4, stream>>>(
        x34, 512, 512L * MNODE,
        c5w, nullptr, bn5s, bn5b, 1, pmax1,
        nullptr, nullptr, nullptr, nullptr, 0, nullptr,
        512, 1024, MNODE);
    k_maxred<<<dim3(16), dim3(256), 0, stream>>>(pmax1, 2, 1024, vec + 1024, 2048);
    // classification head (k_gemv: block per output, coalesced weight rows, 4-batch reuse)
    k_gemv<<<dim3(512), dim3(256), 0, stream>>>(vec, 2048, l1w, 2048, nullptr, bn6hs, bn6hb, 1, c1b, 512);
    k_gemv<<<dim3(256), dim3(256), 0, stream>>>(c1b, 512, l2w, 512, l2b, bn7hs, bn7hb, 1, c2b_, 256);
    k_gemv<<<dim3(15), dim3(256), 0, stream>>>(c2b_, 256, l3w, 256, l3b, nullptr, nullptr, 0, out_cls, 15);
    // conv6: vrep part is n-independent -> per-(b,o) base, then conv over x4
    k_gemv<<<dim3(128), dim3(256), 0, stream>>>(vec, 2048, c6w, 2304, nullptr, nullptr, nullptr, 0, b6, 128);
    k_conv<<<dim3(2, 8, 4), dim3(256), 0, stream>>>(x34 + 256L * MNODE, 256, 512L * MNODE,
                                                    nullptr, 0, 0, c6w + 2048, 2304, b6,
                                                    bn6cs, bn6cb, 1, s6, 128L * MNODE, 128, MNODE);
    k_conv<<<dim3(2, 8, 4), dim3(256), 0, stream>>>(s6, 128, 128L * MNODE, x34, 256, 512L * MNODE,
                                                    c7w, 384, nullptr, bn7cs, bn7cb, 1,
                                                    s7, 128L * MNODE, 128, MNODE);
    // unpool
    k_knn3<<<dim3(1024), dim3(256), 0, stream>>>(x, node, k3i, k3w);
    k_unpool<<<dim3(16384), dim3(256), 0, stream>>>(s7, k3i, k3w, sup);
    // conv8 / conv9 / conv10 (16-wide o-tile)
    k_conv<<<dim3(8, 8, 4), dim3(256), 0, stream>>>(sup, 128, 128L * NPTS, xt1 + 64L * NPTS, 64,
                                                    128L * NPTS, c8w, 192, nullptr, bn8s, bn8b, 1,
                                                    s8, 128L * NPTS, 128, NPTS);
    k_conv<<<dim3(8, 8, 4), dim3(256), 0, stream>>>(s8, 128, 128L * NPTS, xt1, 64, 128L * NPTS,
                                                    c9w, 192, nullptr, bn9s, bn9b, 1,
                                                    s9, 128L * NPTS, 128, NPTS);
    k_conv<<<dim3(8, 1, 4), dim3(256), 0, stream>>>(s9, 128, 128L * NPTS, nullptr, 0, 0,
                                                    c10w, 128, nullptr, nullptr, nullptr, 0,
                                                    out_seg, 2L * NPTS, 2, NPTS);
    (void)in_sizes; (void)n_in; (void)out_size; (void)ws_size;
}

// Round 12
// 1003.638 us; speedup vs baseline: 1.0358x; 1.0358x over previous
//
#include <hip/hip_runtime.h>
#include <math.h>

// Problem constants
#define NPTS 8192
#define MNODE 2048

// ---------------- ws layout (float element offsets) ----------------
#define WS_XT1  0L          // xt1_ [4][128][8192] (x1 ch0-63, x2 ch64-127) — live whole pass
#define WS_A    4194304L    // x34 [4][512][2048] (x3 ch0-255, x4 ch256-511); sort scratch EARLY
#define WS_B    8388608L    // scores [4][8][8192] early; s8 [4][128][8192] later
#define WS_C    12582912L   // h [4][256][2048] early; s6/s7 [4][128][2048] later
#define WS_D    14680064L   // sup [4][128][8192]; s9 later
#define WS_TOPV 18874368L   // [4][2048]
#define WS_TOPI 18882560L   // int [4][2048]
#define WS_NODE 18890752L   // [4][3][2048]
#define WS_MAXP 18915328L   // [4][1024]
#define WS_VEC  18919424L   // [4][2048]
#define WS_C1   18927616L   // [4][512]
#define WS_C2   18929664L   // [4][256]
#define WS_B6   18930688L   // [4][128]
#define WS_K20  18931200L   // int [4][2048][20]; ALSO convmax partial-max scratch (disjoint lifetime)
#define WS_K3I  19095040L   // int [4][8192][3]
#define WS_K3W  19193344L   // [4][8192][3]
// end = 19291648 floats = 73.6 MB

// ---------------- conv1: x[4,3,8192] -> xt1_ ch0-63 ----------------
__global__ __launch_bounds__(256) void k_conv1(const float* __restrict__ x,
                                               const float* __restrict__ W,
                                               const float* __restrict__ sc,
                                               const float* __restrict__ bi,
                                               float* __restrict__ out) {
    int t = blockIdx.x * 256 + threadIdx.x;           // 4*64*8192
    int n = t & 8191, o = (t >> 13) & 63, b = t >> 19;
    const float* xb = x + (long)b * 3 * NPTS;
    float a = W[o * 3 + 0] * xb[n] + W[o * 3 + 1] * xb[NPTS + n] + W[o * 3 + 2] * xb[2 * NPTS + n];
    a = fmaxf(a * sc[o] + bi[o], 0.f);
    out[((long)b * 128 + o) * NPTS + n] = a;
}

// ---------------- conv2: xt1_ ch0-63 -> xt1_ ch64-127 ----------------
__global__ __launch_bounds__(256) void k_conv2(const float* __restrict__ in,
                                               const float* __restrict__ W,
                                               const float* __restrict__ sc,
                                               const float* __restrict__ bi,
                                               float* __restrict__ out) {
    int t = blockIdx.x * 256 + threadIdx.x;
    int n = t & 8191, o = (t >> 13) & 63, b = t >> 19;
    const float* ip = in + (long)b * 128 * NPTS + n;
    const float* wp = W + o * 64;
    float a = 0.f;
#pragma unroll 8
    for (int c = 0; c < 64; ++c) a = fmaf(wp[c], ip[(long)c * NPTS], a);
    out[((long)b * 128 + 64 + o) * NPTS + n] = fmaxf(a * sc[o] + bi[o], 0.f);
}

// 16-output-tile FMA block: reads 4x float4 broadcast from Wl at row c16, FMAs into acc[16]
#define CMAX_FMA16()                                                        \
    {                                                                       \
        const float4* wp4 = reinterpret_cast<const float4*>(Wl + c16);      \
        _Pragma("unroll")                                                   \
        for (int g = 0; g < 4; ++g) {                                       \
            float4 w = wp4[g];                                              \
            acc[4 * g + 0].x = fmaf(w.x, v.x, acc[4 * g + 0].x);            \
            acc[4 * g + 0].y = fmaf(w.x, v.y, acc[4 * g + 0].y);            \
            acc[4 * g + 0].z = fmaf(w.x, v.z, acc[4 * g + 0].z);            \
            acc[4 * g + 0].w = fmaf(w.x, v.w, acc[4 * g + 0].w);            \
            acc[4 * g + 1].x = fmaf(w.y, v.x, acc[4 * g + 1].x);            \
            acc[4 * g + 1].y = fmaf(w.y, v.y, acc[4 * g + 1].y);            \
            acc[4 * g + 1].z = fmaf(w.y, v.z, acc[4 * g + 1].z);            \
            acc[4 * g + 1].w = fmaf(w.y, v.w, acc[4 * g + 1].w);            \
            acc[4 * g + 2].x = fmaf(w.z, v.x, acc[4 * g + 2].x);            \
            acc[4 * g + 2].y = fmaf(w.z, v.y, acc[4 * g + 2].y);            \
            acc[4 * g + 2].z = fmaf(w.z, v.z, acc[4 * g + 2].z);            \
            acc[4 * g + 2].w = fmaf(w.z, v.w, acc[4 * g + 2].w);            \
            acc[4 * g + 3].x = fmaf(w.w, v.x, acc[4 * g + 3].x);            \
            acc[4 * g + 3].y = fmaf(w.w, v.y, acc[4 * g + 3].y);            \
            acc[4 * g + 3].z = fmaf(w.w, v.z, acc[4 * g + 3].z);            \
            acc[4 * g + 3].w = fmaf(w.w, v.w, acc[4 * g + 3].w);            \
        }                                                                   \
    }

// ---------------- fused conv(+cbias)(+bn)(+relu) + partial max, DUAL param set ----------------
// 16-wide O-tile, Wl transposed [C][16], 1-deep prefetch (R10-proven loop).
// LDS ALIAS: red[16][257] reuses Wl's space (Wl dead after c-loop; barrier guards).
// LDS/block = max(16C, 4112) floats -> 16.4KB (C=128), 32.8KB (C=512).
__global__ __launch_bounds__(256) void k_convmax(
        const float* __restrict__ in, int C, long ibs,
        const float* __restrict__ W1, const float* __restrict__ cb1,
        const float* __restrict__ sc1, const float* __restrict__ bi1, int relu1,
        float* __restrict__ pmax1,
        const float* __restrict__ W2, const float* __restrict__ cb2,
        const float* __restrict__ sc2, const float* __restrict__ bi2, int relu2,
        float* __restrict__ pmax2,
        int wpitch, int O, int Nn) {
    extern __shared__ float sm_[];
    float* Wl = sm_;              // [C][16]
    float* red = sm_;             // [16][257] — ALIASES Wl (disjoint lifetime)
    int b = blockIdx.z;
    int ns = blockIdx.x;
    int oblocks = O >> 4;
    int setid = (int)blockIdx.y / oblocks;          // uniform per block
    int og0 = ((int)blockIdx.y - setid * oblocks) * 16;
    const float* W  = setid ? W2 : W1;
    const float* cb = setid ? cb2 : cb1;
    const float* sc = setid ? sc2 : sc1;
    const float* bi = setid ? bi2 : bi1;
    int do_relu     = setid ? relu2 : relu1;
    float* pmax     = setid ? pmax2 : pmax1;
    for (int t = threadIdx.x; t < 16 * C; t += 256) {
        int c = t >> 4, o = t & 15;
        Wl[t] = W[(long)(og0 + o) * wpitch + c];
    }
    __syncthreads();
    int n0 = ns * 1024 + threadIdx.x * 4;
    float4 acc[16];
#pragma unroll
    for (int o = 0; o < 16; ++o) acc[o] = make_float4(0.f, 0.f, 0.f, 0.f);
    const float* p = in + (long)b * ibs + n0;
    float4 v = *reinterpret_cast<const float4*>(p);
    for (int c = 0; c < C - 1; ++c) {
        float4 vn = *reinterpret_cast<const float4*>(p + (long)(c + 1) * Nn);  // prefetch
        int c16 = c * 16;
        CMAX_FMA16();
        v = vn;
    }
    {
        int c16 = (C - 1) * 16;
        CMAX_FMA16();
    }
    // bn/relu + horizontal max4 into registers, THEN barrier (Wl dead), stage, tree-reduce
    float h2[16];
#pragma unroll
    for (int o = 0; o < 16; ++o) {
        float cbv = cb ? cb[og0 + o] : 0.f;
        float scv = sc ? sc[og0 + o] : 1.f;
        float biv = bi ? bi[og0 + o] : 0.f;
        float4 a = acc[o];
        float vx = (a.x + cbv) * scv + biv;
        float vy = (a.y + cbv) * scv + biv;
        float vz = (a.z + cbv) * scv + biv;
        float vw = (a.w + cbv) * scv + biv;
        if (do_relu) {
            vx = fmaxf(vx, 0.f); vy = fmaxf(vy, 0.f);
            vz = fmaxf(vz, 0.f); vw = fmaxf(vw, 0.f);
        }
        h2[o] = fmaxf(fmaxf(vx, vy), fmaxf(vz, vw));
    }
    __syncthreads();   // all Wl reads complete before red overwrites it
#pragma unroll
    for (int o = 0; o < 16; ++o) red[o * 257 + threadIdx.x] = h2[o];
    __syncthreads();
    for (int ls = 7; ls >= 0; --ls) {
        int s = 1 << ls;
        for (int w = threadIdx.x; w < 16 * s; w += 256) {
            int o = w >> ls, i = w & (s - 1);
            float* r = red + o * 257;
            r[i] = fmaxf(r[i], r[i + s]);
        }
        __syncthreads();
    }
    if (threadIdx.x < 16)
        pmax[((long)ns * 4 + b) * O + og0 + threadIdx.x] = red[threadIdx.x * 257];
}

// finalize: out[b*obs + o] = max over nsplit partials
__global__ __launch_bounds__(256) void k_maxred(const float* __restrict__ pmax, int nsplit,
                                                int O, float* __restrict__ out, long obs) {
    int t = blockIdx.x * 256 + threadIdx.x;
    if (t >= 4 * O) return;
    int o = t % O, b = t / O;
    float m = -3.0e38f;
    for (int s = 0; s < nsplit; ++s) m = fmaxf(m, pmax[((long)s * 4 + b) * O + o]);
    out[(long)b * obs + o] = m;
}

// ---------------- generic conv(+extra)(+bn)(+relu), up to 2 concat inputs ----------------
// block 256, grid (Nn/1024, ceil(O/8), B). 8-wide o-tile (R10-proven),
// Wl transposed [Ct][8] zero-padded, 2x float4 weight reads per c, 1-deep prefetch.
#define CONV_FMA8()                                                         \
    {                                                                       \
        const float4* wp4 = reinterpret_cast<const float4*>(Wl + c8);       \
        _Pragma("unroll")                                                   \
        for (int g = 0; g < 2; ++g) {                                       \
            float4 w = wp4[g];                                              \
            acc[4 * g + 0].x = fmaf(w.x, v.x, acc[4 * g + 0].x);            \
            acc[4 * g + 0].y = fmaf(w.x, v.y, acc[4 * g + 0].y);            \
            acc[4 * g + 0].z = fmaf(w.x, v.z, acc[4 * g + 0].z);            \
            acc[4 * g + 0].w = fmaf(w.x, v.w, acc[4 * g + 0].w);            \
            acc[4 * g + 1].x = fmaf(w.y, v.x, acc[4 * g + 1].x);            \
            acc[4 * g + 1].y = fmaf(w.y, v.y, acc[4 * g + 1].y);            \
            acc[4 * g + 1].z = fmaf(w.y, v.z, acc[4 * g + 1].z);            \
            acc[4 * g + 1].w = fmaf(w.y, v.w, acc[4 * g + 1].w);            \
            acc[4 * g + 2].x = fmaf(w.z, v.x, acc[4 * g + 2].x);            \
            acc[4 * g + 2].y = fmaf(w.z, v.y, acc[4 * g + 2].y);            \
            acc[4 * g + 2].z = fmaf(w.z, v.z, acc[4 * g + 2].z);            \
            acc[4 * g + 2].w = fmaf(w.z, v.w, acc[4 * g + 2].w);            \
            acc[4 * g + 3].x = fmaf(w.w, v.x, acc[4 * g + 3].x);            \
            acc[4 * g + 3].y = fmaf(w.w, v.y, acc[4 * g + 3].y);            \
            acc[4 * g + 3].z = fmaf(w.w, v.z, acc[4 * g + 3].z);            \
            acc[4 * g + 3].w = fmaf(w.w, v.w, acc[4 * g + 3].w);            \
        }                                                                   \
    }

__global__ __launch_bounds__(256) void k_conv(const float* __restrict__ in1, int C1, long ibs1,
                                              const float* __restrict__ in2, int C2, long ibs2,
                                              const float* __restrict__ W, int wpitch,
                                              const float* __restrict__ extra,
                                              const float* __restrict__ sc,
                                              const float* __restrict__ bi, int do_relu,
                                              float* __restrict__ out, long obs, int O, int Nn) {
    __shared__ float Wl[384 * 8];
    int b = blockIdx.z;
    int og0 = blockIdx.y * 8;
    int on = O - og0; if (on > 8) on = 8;
    int Ct = C1 + C2;
    for (int t = threadIdx.x; t < Ct * 8; t += 256) {
        int c = t >> 3, o = t & 7;
        Wl[t] = (o < on) ? W[(long)(og0 + o) * wpitch + c] : 0.f;
    }
    __syncthreads();
    int n0 = blockIdx.x * 1024 + threadIdx.x * 4;
    float4 acc[8];
#pragma unroll
    for (int o = 0; o < 8; ++o) acc[o] = make_float4(0.f, 0.f, 0.f, 0.f);
    const float* p1 = in1 + (long)b * ibs1 + n0;
    {
        float4 v = *reinterpret_cast<const float4*>(p1);
        for (int c = 0; c < C1 - 1; ++c) {
            float4 vn = *reinterpret_cast<const float4*>(p1 + (long)(c + 1) * Nn);
            int c8 = c * 8;
            CONV_FMA8();
            v = vn;
        }
        int c8 = (C1 - 1) * 8;
        CONV_FMA8();
    }
    if (in2) {
        const float* p2 = in2 + (long)b * ibs2 + n0;
        float4 v = *reinterpret_cast<const float4*>(p2);
        for (int c = 0; c < C2 - 1; ++c) {
            float4 vn = *reinterpret_cast<const float4*>(p2 + (long)(c + 1) * Nn);
            int c8 = (C1 + c) * 8;
            CONV_FMA8();
            v = vn;
        }
        int c8 = (Ct - 1) * 8;
        CONV_FMA8();
    }
#pragma unroll
    for (int o = 0; o < 8; ++o) {
        if (o < on) {
            float e = extra ? extra[(long)b * O + og0 + o] : 0.f;
            float s = sc ? sc[og0 + o] : 1.f;
            float bv = bi ? bi[og0 + o] : 0.f;
            float4 a = acc[o];
            a.x = (a.x + e) * s + bv;
            a.y = (a.y + e) * s + bv;
            a.z = (a.z + e) * s + bv;
            a.w = (a.w + e) * s + bv;
            if (do_relu) {
                a.x = fmaxf(a.x, 0.f); a.y = fmaxf(a.y, 0.f);
                a.z = fmaxf(a.z, 0.f); a.w = fmaxf(a.w, 0.f);
            }
            *reinterpret_cast<float4*>(out + (long)b * obs + (long)(og0 + o) * Nn + n0) = a;
        }
    }
}

// ---------------- scores[b][e][n] = sigmoid(sum_c feat*vec), all 8 e per block ----------------
__global__ __launch_bounds__(256) void k_scores(const float* __restrict__ feat,
                                                const float* __restrict__ maxp,
                                                float* __restrict__ scores) {
    __shared__ float vl[1024];
    int b = blockIdx.z;
    for (int t = threadIdx.x; t < 1024; t += 256) vl[t] = maxp[b * 1024 + t];
    __syncthreads();
    int n0 = blockIdx.x * 1024 + threadIdx.x * 4;
    float4 acc[8];
#pragma unroll
    for (int e = 0; e < 8; ++e) acc[e] = make_float4(0.f, 0.f, 0.f, 0.f);
    const float* p = feat + (long)b * 128 * NPTS + n0;
    for (int c = 0; c < 128; ++c) {
        float4 v = *reinterpret_cast<const float4*>(p + (long)c * NPTS);
#pragma unroll
        for (int e = 0; e < 8; ++e) {
            float w = vl[c * 8 + e];
            acc[e].x = fmaf(w, v.x, acc[e].x);
            acc[e].y = fmaf(w, v.y, acc[e].y);
            acc[e].z = fmaf(w, v.z, acc[e].z);
            acc[e].w = fmaf(w, v.w, acc[e].w);
        }
    }
#pragma unroll
    for (int e = 0; e < 8; ++e) {
        float4 a = acc[e];
        a.x = 1.f / (1.f + expf(-a.x));
        a.y = 1.f / (1.f + expf(-a.y));
        a.z = 1.f / (1.f + expf(-a.z));
        a.w = 1.f / (1.f + expf(-a.w));
        *reinterpret_cast<float4*>(scores + ((long)b * 8 + e) * NPTS + n0) = a;
    }
}

// ---------------- hierarchical exact sorted top-256 per (b,e) ----------------
__global__ __launch_bounds__(256) void k_sorta(const float* __restrict__ scores,
                                               unsigned int* __restrict__ kout,
                                               unsigned short* __restrict__ iout) {
    __shared__ unsigned int kv[1024];
    __shared__ unsigned short ki[1024];
    int ch = blockIdx.x & 7;
    const float* sp = scores + (long)(blockIdx.x >> 3) * NPTS + ch * 1024;
    for (int t = threadIdx.x; t < 1024; t += 256) {
        kv[t] = __float_as_uint(sp[t]) ^ 0xFFFFFFFFu;
        ki[t] = (unsigned short)(ch * 1024 + t);
    }
    __syncthreads();
    for (int k = 2; k <= 1024; k <<= 1) {
        for (int j = k >> 1; j > 0; j >>= 1) {
            for (int t = threadIdx.x; t < 1024; t += 256) {
                int ixj = t ^ j;
                if (ixj > t) {
                    unsigned int va = kv[t], vb = kv[ixj];
                    unsigned short ia = ki[t], ib = ki[ixj];
                    bool up = ((t & k) == 0);
                    bool gt = (va > vb) || (va == vb && ia > ib);
                    if (gt == up) { kv[t] = vb; kv[ixj] = va; ki[t] = ib; ki[ixj] = ia; }
                }
            }
            __syncthreads();
        }
    }
    if (threadIdx.x < 256) {
        kout[blockIdx.x * 256 + threadIdx.x] = kv[threadIdx.x];
        iout[blockIdx.x * 256 + threadIdx.x] = ki[threadIdx.x];
    }
}

__global__ __launch_bounds__(512) void k_sortb(const unsigned int* __restrict__ kin,
                                               const unsigned short* __restrict__ iin,
                                               float* __restrict__ topv,
                                               int* __restrict__ topi) {
    __shared__ unsigned int kv[2048];
    __shared__ unsigned short ki[2048];
    int be = blockIdx.x, b = be >> 3, e = be & 7;
    for (int t = threadIdx.x; t < 2048; t += 512) {
        kv[t] = kin[be * 2048 + t];
        ki[t] = iin[be * 2048 + t];
    }
    __syncthreads();
    for (int k = 2; k <= 2048; k <<= 1) {
        for (int j = k >> 1; j > 0; j >>= 1) {
            for (int t = threadIdx.x; t < 2048; t += 512) {
                int ixj = t ^ j;
                if (ixj > t) {
                    unsigned int va = kv[t], vb = kv[ixj];
                    unsigned short ia = ki[t], ib = ki[ixj];
                    bool up = ((t & k) == 0);
                    bool gt = (va > vb) || (va == vb && ia > ib);
                    if (gt == up) { kv[t] = vb; kv[ixj] = va; ki[t] = ib; ki[ixj] = ia; }
                }
            }
            __syncthreads();
        }
    }
    for (int r = threadIdx.x; r < 256; r += 512) {
        int j = r * 8 + e;  // torch-order reshape: values[b, r*8+e] = v[b,e,r]
        topv[b * 2048 + j] = __uint_as_float(kv[r] ^ 0xFFFFFFFFu);
        topi[b * 2048 + j] = (int)ki[r];
    }
}

// ---------------- pool gather: node, node_static (coords) ----------------
__global__ __launch_bounds__(256) void k_poolgather(const float* __restrict__ xyz,
                                                    const float* __restrict__ topv,
                                                    const int* __restrict__ topi,
                                                    float* __restrict__ node_ws,
                                                    float* __restrict__ out_node,
                                                    float* __restrict__ out_nstat) {
    int t = blockIdx.x * 256 + threadIdx.x;  // 4*2048
    int j = t & 2047, b = t >> 11;
    int i = topi[b * 2048 + j];
    float v = topv[b * 2048 + j];
#pragma unroll
    for (int k = 0; k < 3; ++k) {
        float sx = xyz[((long)b * 3 + k) * NPTS + i];
        float nd = sx * v;
        out_nstat[((long)b * 3 + k) * MNODE + j] = sx;
        out_node[((long)b * 3 + k) * MNODE + j] = nd;
        node_ws[((long)b * 3 + k) * MNODE + j] = nd;
    }
}

// ---------------- nf1: h ch0-127 = feat gathered * values ----------------
__global__ __launch_bounds__(256) void k_nf1(const float* __restrict__ feat,
                                             const float* __restrict__ topv,
                                             const int* __restrict__ topi,
                                             float* __restrict__ h) {
    int t = blockIdx.x * 256 + threadIdx.x;  // 4*128*2048
    int j = t & 2047, c = (t >> 11) & 127, b = t >> 18;
    int i = topi[b * 2048 + j];
    float v = topv[b * 2048 + j];
    h[((long)b * 256 + c) * MNODE + j] = feat[((long)b * 128 + c) * NPTS + i] * v;
}

// ---------------- knn20 (block-per-node): exact stable top-20 ----------------
__device__ __forceinline__ unsigned int fsortbits(float f) {
    unsigned int u = __float_as_uint(f);
    return u ^ ((unsigned int)((int)u >> 31) | 0x80000000u);
}

__global__ __launch_bounds__(256) void k_knn20(const float* __restrict__ xyz,
                                               const float* __restrict__ node,
                                               int* __restrict__ k20) {
    __shared__ unsigned int s1[256];
    __shared__ int s2[256];
    __shared__ int lcnt;
    int m = blockIdx.x & 2047, b = blockIdx.x >> 11;
    int t = threadIdx.x;
    float nx = node[((long)b * 3 + 0) * MNODE + m];
    float ny = node[((long)b * 3 + 1) * MNODE + m];
    float nz = node[((long)b * 3 + 2) * MNODE + m];
    float sm = nx * nx + ny * ny + nz * nz;
    const float* xb = xyz + (long)b * 3 * NPTS;
    unsigned int kmin = 0xFFFFFFFFu;
    for (int i = 0; i < 32; ++i) {
        int n = i * 256 + t;
        float px = xb[n], py = xb[NPTS + n], pz = xb[2 * NPTS + n];
        float d = (px * px + py * py + pz * pz) + sm - 2.f * (px * nx + py * ny + pz * nz);
        unsigned int key = fsortbits(d);
        kmin = key < kmin ? key : kmin;
    }
    s1[t] = kmin;
    if (t == 0) lcnt = 0;
    __syncthreads();
    for (int k = 2; k <= 256; k <<= 1) {
        for (int j = k >> 1; j > 0; j >>= 1) {
            int ixj = t ^ j;
            if (ixj > t) {
                unsigned int va = s1[t], vb = s1[ixj];
                bool up = ((t & k) == 0);
                if ((va > vb) == up) { s1[t] = vb; s1[ixj] = va; }
            }
            __syncthreads();
        }
    }
    unsigned int keyT = s1[19];
    __syncthreads();
    for (int i = 0; i < 32; ++i) {
        int n = i * 256 + t;
        float px = xb[n], py = xb[NPTS + n], pz = xb[2 * NPTS + n];
        float d = (px * px + py * py + pz * pz) + sm - 2.f * (px * nx + py * ny + pz * nz);
        unsigned int key = fsortbits(d);
        if (key <= keyT) {
            int p = atomicAdd(&lcnt, 1);
            if (p < 128) { s1[p] = key; s2[p] = n; }
        }
    }
    __syncthreads();
    int cnt = lcnt;  // uniform across block
    if (cnt <= 128) {
        if (t >= cnt && t < 128) { s1[t] = 0xFFFFFFFFu; s2[t] = 0x7FFFFFFF; }
        __syncthreads();
        for (int k = 2; k <= 128; k <<= 1) {
            for (int j = k >> 1; j > 0; j >>= 1) {
                if (t < 128) {
                    int ixj = t ^ j;
                    if (ixj > t) {
                        unsigned int va = s1[t], vb = s1[ixj];
                        int ia = s2[t], ib = s2[ixj];
                        bool up = ((t & k) == 0);
                        bool gt = (va > vb) || (va == vb && ia > ib);
                        if (gt == up) { s1[t] = vb; s1[ixj] = va; s2[t] = ib; s2[ixj] = ia; }
                    }
                }
                __syncthreads();
            }
        }
        if (t < 20) k20[((long)b * 2048 + m) * 20 + t] = s2[t];
    } else {
        unsigned int lastk = 0u; int lasti = -1;
        for (int r = 0; r < 20; ++r) {
            unsigned int bk = 0xFFFFFFFFu; int bi = 0x7FFFFFFF;
            for (int i = 0; i < 32; ++i) {
                int n = i * 256 + t;
                float px = xb[n], py = xb[NPTS + n], pz = xb[2 * NPTS + n];
                float d = (px * px + py * py + pz * pz) + sm - 2.f * (px * nx + py * ny + pz * nz);
                unsigned int key = fsortbits(d);
                bool gtlast = (key > lastk) || (key == lastk && n > lasti);
                bool ltbest = (key < bk) || (key == bk && n < bi);
                if (gtlast && ltbest) { bk = key; bi = n; }
            }
            s1[t] = bk; s2[t] = bi;
            __syncthreads();
            for (int s = 128; s > 0; s >>= 1) {
                if (t < s) {
                    unsigned int vo = s1[t + s]; int io = s2[t + s];
                    unsigned int vm = s1[t]; int im = s2[t];
                    if (vo < vm || (vo == vm && io < im)) { s1[t] = vo; s2[t] = io; }
                }
                __syncthreads();
            }
            if (t == 0) k20[((long)b * 2048 + m) * 20 + r] = s2[0];
            lastk = s1[0]; lasti = s2[0];
            __syncthreads();
        }
    }
}

// ---------------- aggregate: h ch128-255 = max over 20 gathered feats ----------------
__global__ __launch_bounds__(256) void k_agg(const float* __restrict__ feat,
                                             const int* __restrict__ k20,
                                             float* __restrict__ h) {
    int t = blockIdx.x * 256 + threadIdx.x;  // 4*128*2048
    int m = t & 2047, c = (t >> 11) & 127, b = t >> 18;
    const int* ip = k20 + ((long)b * 2048 + m) * 20;
    const float* fb = feat + ((long)b * 128 + c) * NPTS;
    float mx = -3.0e38f;
#pragma unroll
    for (int q = 0; q < 20; ++q) mx = fmaxf(mx, fb[ip[q] & 8191]);  // mask = fault isolation
    h[((long)b * 256 + 128 + c) * MNODE + m] = mx;
}

// ---------------- gemv: block per output o, all 4 batches; coalesced row read ----------------
__global__ __launch_bounds__(256) void k_gemv(const float* __restrict__ in, int C,
                                              const float* __restrict__ W, int wpitch,
                                              const float* __restrict__ lb,
                                              const float* __restrict__ sc,
                                              const float* __restrict__ bi, int do_relu,
                                              float* __restrict__ out, int O) {
    __shared__ float red[256];
    int o = blockIdx.x;
    int t = threadIdx.x;
    const float* wp = W + (long)o * wpitch;
    float a0 = 0.f, a1 = 0.f, a2 = 0.f, a3 = 0.f;
    for (int c = t * 4; c < C; c += 1024) {
        float4 w = *reinterpret_cast<const float4*>(wp + c);
        float4 v0 = *reinterpret_cast<const float4*>(in + 0L * C + c);
        float4 v1 = *reinterpret_cast<const float4*>(in + 1L * C + c);
        float4 v2 = *reinterpret_cast<const float4*>(in + 2L * C + c);
        float4 v3 = *reinterpret_cast<const float4*>(in + 3L * C + c);
        a0 += w.x * v0.x + w.y * v0.y + w.z * v0.z + w.w * v0.w;
        a1 += w.x * v1.x + w.y * v1.y + w.z * v1.z + w.w * v1.w;
        a2 += w.x * v2.x + w.y * v2.y + w.z * v2.z + w.w * v2.w;
        a3 += w.x * v3.x + w.y * v3.y + w.z * v3.z + w.w * v3.w;
    }
    float lbv = lb ? lb[o] : 0.f;
    float scv = sc ? sc[o] : 1.f;
    float biv = bi ? bi[o] : 0.f;
#pragma unroll
    for (int b = 0; b < 4; ++b) {
        float a = (b == 0) ? a0 : (b == 1) ? a1 : (b == 2) ? a2 : a3;
        __syncthreads();
        red[t] = a;
        __syncthreads();
        for (int s2 = 128; s2 > 0; s2 >>= 1) {
            if (t < s2) red[t] += red[t + s2];
            __syncthreads();
        }
        if (t == 0) {
            float r = (red[0] + lbv) * scv + biv;
            if (do_relu) r = fmaxf(r, 0.f);
            out[(long)b * O + o] = r;
        }
    }
}

// ---------------- unpool knn3: block = 32 points x 8 threads/point, nodes staged in LDS ----
__global__ __launch_bounds__(256) void k_knn3(const float* __restrict__ xyz,
                                              const float* __restrict__ node,
                                              int* __restrict__ k3i, float* __restrict__ k3w) {
    __shared__ float sx[2048], sy[2048], sz[2048], sn[2048];
    __shared__ float md[256][3];
    __shared__ int   mi[256][3];
    int b = blockIdx.x >> 8;                 // 256 blocks per batch
    int pbase = (blockIdx.x & 255) * 32;
    int t = threadIdx.x;
    const float* nb = node + (long)b * 3 * MNODE;
    for (int j = t; j < 2048; j += 256) {
        float qx = nb[j], qy = nb[MNODE + j], qz = nb[2 * MNODE + j];
        sx[j] = qx; sy[j] = qy; sz[j] = qz;
        sn[j] = qx * qx + qy * qy + qz * qz;   // reference computes |b|^2 once per node
    }
    __syncthreads();
    int i = t & 31, q = t >> 5;
    int n = pbase + i;
    float px = xyz[((long)b * 3 + 0) * NPTS + n];
    float py = xyz[((long)b * 3 + 1) * NPTS + n];
    float pz = xyz[((long)b * 3 + 2) * NPTS + n];
    float sp = px * px + py * py + pz * pz;
    float d0 = 3.0e38f, d1 = 3.0e38f, d2 = 3.0e38f;
    int i0 = 0, i1 = 0, i2 = 0;
    int m0 = q * 256;
#pragma unroll 4
    for (int k = 0; k < 256; ++k) {
        int m = m0 + k;
        float d = (sp + sn[m]) - 2.f * (px * sx[m] + py * sy[m] + pz * sz[m]);
        if (d < d2) {
            d2 = d; i2 = m;
            if (d2 < d1) { float td = d1; d1 = d2; d2 = td; int ti = i1; i1 = i2; i2 = ti; }
            if (d1 < d0) { float td = d0; d0 = d1; d1 = td; int ti = i0; i0 = i1; i1 = ti; }
        }
    }
    md[t][0] = d0; md[t][1] = d1; md[t][2] = d2;
    mi[t][0] = i0; mi[t][1] = i1; mi[t][2] = i2;
    __syncthreads();
    if (t < 32) {
        int p0 = 0, p1 = 0, p2 = 0, p3 = 0, p4 = 0, p5 = 0, p6 = 0, p7 = 0;
        float rd[3]; int ri[3];
#pragma unroll
        for (int r = 0; r < 3; ++r) {
            float bestd = 3.0e38f; int besti = 0x7FFFFFFF; int bestq = -1;
#define KNN3_HEAD(QQ, PV)                                                              \
            {                                                                          \
                float dd = md[(QQ) * 32 + t][PV]; int ii = mi[(QQ) * 32 + t][PV];      \
                if (dd < bestd || (dd == bestd && ii < besti)) {                       \
                    bestd = dd; besti = ii; bestq = (QQ);                              \
                }                                                                      \
            }
            KNN3_HEAD(0, p0) KNN3_HEAD(1, p1) KNN3_HEAD(2, p2) KNN3_HEAD(3, p3)
            KNN3_HEAD(4, p4) KNN3_HEAD(5, p5) KNN3_HEAD(6, p6) KNN3_HEAD(7, p7)
#undef KNN3_HEAD
            rd[r] = bestd; ri[r] = besti;
            p0 += (bestq == 0); p1 += (bestq == 1); p2 += (bestq == 2); p3 += (bestq == 3);
            p4 += (bestq == 4); p5 += (bestq == 5); p6 += (bestq == 6); p7 += (bestq == 7);
        }
        // reference: w = softmax(-negd) = softmax over the squared distances themselves
        float mxd = fmaxf(rd[0], fmaxf(rd[1], rd[2]));
        float e0 = expf(rd[0] - mxd), e1 = expf(rd[1] - mxd), e2 = expf(rd[2] - mxd);
        float inv = 1.f / (e0 + e1 + e2);
        long base = ((long)b * NPTS + pbase + t) * 3;
        k3i[base] = ri[0]; k3i[base + 1] = ri[1]; k3i[base + 2] = ri[2];
        k3w[base] = e0 * inv; k3w[base + 1] = e1 * inv; k3w[base + 2] = e2 * inv;
    }
}

__global__ __launch_bounds__(256) void k_unpool(const float* __restrict__ s7,
                                                const int* __restrict__ k3i,
                                                const float* __restrict__ k3w,
                                                float* __restrict__ sup) {
    int t = blockIdx.x * 256 + threadIdx.x;  // 4*128*8192
    int n = t & 8191, c = (t >> 13) & 127, b = t >> 20;
    long base = ((long)b * NPTS + n) * 3;
    const float* spp = s7 + ((long)b * 128 + c) * MNODE;
    float a = k3w[base] * spp[k3i[base]] + k3w[base + 1] * spp[k3i[base + 1]] +
              k3w[base + 2] * spp[k3i[base + 2]];
    sup[((long)b * 128 + c) * NPTS + n] = a;
}

extern "C" void kernel_launch(void* const* d_in, const int* in_sizes, int n_in,
                              void* d_out, int out_size, void* d_ws, size_t ws_size,
                              hipStream_t stream) {
    const float* x     = (const float*)d_in[0];
    const float* c1w   = (const float*)d_in[1];
    const float* c2w   = (const float*)d_in[2];
    const float* c2mw  = (const float*)d_in[3];
    const float* c3w   = (const float*)d_in[4];
    const float* c4w   = (const float*)d_in[5];
    const float* c5w   = (const float*)d_in[6];
    const float* c6w   = (const float*)d_in[7];
    const float* c7w   = (const float*)d_in[8];
    const float* c8w   = (const float*)d_in[9];
    const float* c9w   = (const float*)d_in[10];
    const float* c10w  = (const float*)d_in[11];
    const float* bn1s  = (const float*)d_in[12]; const float* bn1b  = (const float*)d_in[13];
    const float* bn2s  = (const float*)d_in[14]; const float* bn2b  = (const float*)d_in[15];
    const float* bn2ms = (const float*)d_in[16]; const float* bn2mb = (const float*)d_in[17];
    const float* bn3s  = (const float*)d_in[18]; const float* bn3b  = (const float*)d_in[19];
    const float* bn4s  = (const float*)d_in[20]; const float* bn4b  = (const float*)d_in[21];
    const float* bn5s  = (const float*)d_in[22]; const float* bn5b  = (const float*)d_in[23];
    const float* bn6cs = (const float*)d_in[24]; const float* bn6cb = (const float*)d_in[25];
    const float* bn7cs = (const float*)d_in[26]; const float* bn7cb = (const float*)d_in[27];
    const float* bn8s  = (const float*)d_in[28]; const float* bn8b  = (const float*)d_in[29];
    const float* bn9s  = (const float*)d_in[30]; const float* bn9b  = (const float*)d_in[31];
    const float* bn6hs = (const float*)d_in[32]; const float* bn6hb = (const float*)d_in[33];
    const float* bn7hs = (const float*)d_in[34]; const float* bn7hb = (const float*)d_in[35];
    const float* poolw = (const float*)d_in[36]; const float* poolb = (const float*)d_in[37];
    const float* l1w   = (const float*)d_in[38];
    const float* l2w   = (const float*)d_in[39]; const float* l2b   = (const float*)d_in[40];
    const float* l3w   = (const float*)d_in[41]; const float* l3b   = (const float*)d_in[42];

    float* ws   = (float*)d_ws;
    float* xt1  = ws + WS_XT1;
    float* x34  = ws + WS_A;
    float* scor = ws + WS_B;
    float* s8   = ws + WS_B;                 // aliases scores (dead by then)
    float* hbuf = ws + WS_C;
    float* s6   = ws + WS_C;                 // aliases h (dead after conv3)
    float* s7   = ws + WS_C + 1048576L;
    float* sup  = ws + WS_D;
    float* s9   = ws + WS_D;                 // aliases sup (dead after conv8)
    float* topv = ws + WS_TOPV;
    int*   topi = (int*)(ws + WS_TOPI);
    float* node = ws + WS_NODE;
    float* maxp = ws + WS_MAXP;
    float* vec  = ws + WS_VEC;
    float* c1b  = ws + WS_C1;
    float* c2b_ = ws + WS_C2;
    float* b6   = ws + WS_B6;
    int*   k20  = (int*)(ws + WS_K20);
    float* pmax1 = ws + WS_K20;              // convmax partial scratch (k20 lifetime-disjoint)
    float* pmax2 = ws + WS_K20 + 32768;      // second set (8 splits * 4 * 1024)
    int*   k3i  = (int*)(ws + WS_K3I);
    float* k3w  = ws + WS_K3W;
    // sort scratch aliases x34 region (dead until conv3)
    unsigned int*   sskeys = (unsigned int*)(ws + WS_A);
    unsigned short* ssidx  = (unsigned short*)(ws + WS_A + 65536);

    float* out       = (float*)d_out;
    float* out_cls   = out;                  // [4,15]
    float* out_seg   = out + 60;             // [4,2,8192]
    float* out_node  = out + 60 + 65536;     // [4,3,2048]
    float* out_nstat = out_node + 24576;     // [4,3,2048]

    // x1, x2 -> xt1_
    k_conv1<<<dim3(8192), dim3(256), 0, stream>>>(x, c1w, bn1s, bn1b, xt1);
    k_conv2<<<dim3(8192), dim3(256), 0, stream>>>(xt1, c2w, bn2s, bn2b, xt1);
    // FUSED conv2m + pool-proj: one launch, 2 param sets; LDS = max(16C,4112) floats
    k_convmax<<<dim3(8, 128, 4), dim3(256), 16 * 257 * 4, stream>>>(
        xt1, 128, 128L * NPTS,
        c2mw, nullptr, bn2ms, bn2mb, 1, pmax1,
        poolw, poolb, nullptr, nullptr, 0, pmax2,
        128, 1024, NPTS);
    k_maxred<<<dim3(16), dim3(256), 0, stream>>>(pmax1, 8, 1024, vec, 2048);
    k_maxred<<<dim3(16), dim3(256), 0, stream>>>(pmax2, 8, 1024, maxp, 1024);
    // scores
    k_scores<<<dim3(8, 1, 4), dim3(256), 0, stream>>>(xt1, maxp, scor);
    // exact top-256 per (b,e): hierarchical chunk-sort + merge-sort
    k_sorta<<<dim3(256), dim3(256), 0, stream>>>(scor, sskeys, ssidx);
    k_sortb<<<dim3(32), dim3(512), 0, stream>>>(sskeys, ssidx, topv, topi);
    // node / node_static / nf1
    k_poolgather<<<dim3(32), dim3(256), 0, stream>>>(x, topv, topi, node, out_node, out_nstat);
    k_nf1<<<dim3(4096), dim3(256), 0, stream>>>(xt1, topv, topi, hbuf);
    // aggregate (knn20 block-per-node + gather-max)
    k_knn20<<<dim3(8192), dim3(256), 0, stream>>>(x, node, k20);
    k_agg<<<dim3(4096), dim3(256), 0, stream>>>(xt1, k20, hbuf);
    // conv3 / conv4 -> x34 (8-wide o-tile, R10 config)
    k_conv<<<dim3(2, 32, 4), dim3(256), 0, stream>>>(hbuf, 256, 256L * MNODE, nullptr, 0, 0,
                                                     c3w, 256, nullptr, bn3s, bn3b, 1,
                                                     x34, 512L * MNODE, 256, MNODE);
    k_conv<<<dim3(2, 32, 4), dim3(256), 0, stream>>>(x34, 256, 512L * MNODE, nullptr, 0, 0,
                                                     c4w, 256, nullptr, bn4s, bn4b, 1,
                                                     x34 + 256L * MNODE, 512L * MNODE, 256, MNODE);
    // conv5 fused max -> vector[:,1024:2048]; LDS = 16*512 floats (red aliases)
    k_convmax<<<dim3(2, 64, 4), dim3(256), 16 * 512 * 4, stream>>>(
        x34, 512, 512L * MNODE,
        c5w, nullptr, bn5s, bn5b, 1, pmax1,
        nullptr, nullptr, nullptr, nullptr, 0, nullptr,
        512, 1024, MNODE);
    k_maxred<<<dim3(16), dim3(256), 0, stream>>>(pmax1, 2, 1024, vec + 1024, 2048);
    // classification head (k_gemv: block per output, coalesced weight rows, 4-batch reuse)
    k_gemv<<<dim3(512), dim3(256), 0, stream>>>(vec, 2048, l1w, 2048, nullptr, bn6hs, bn6hb, 1, c1b, 512);
    k_gemv<<<dim3(256), dim3(256), 0, stream>>>(c1b, 512, l2w, 512, l2b, bn7hs, bn7hb, 1, c2b_, 256);
    k_gemv<<<dim3(15), dim3(256), 0, stream>>>(c2b_, 256, l3w, 256, l3b, nullptr, nullptr, 0, out_cls, 15);
    // conv6: vrep part is n-independent -> per-(b,o) base, then conv over x4
    k_gemv<<<dim3(128), dim3(256), 0, stream>>>(vec, 2048, c6w, 2304, nullptr, nullptr, nullptr, 0, b6, 128);
    k_conv<<<dim3(2, 16, 4), dim3(256), 0, stream>>>(x34 + 256L * MNODE, 256, 512L * MNODE,
                                                     nullptr, 0, 0, c6w + 2048, 2304, b6,
                                                     bn6cs, bn6cb, 1, s6, 128L * MNODE, 128, MNODE);
    k_conv<<<dim3(2, 16, 4), dim3(256), 0, stream>>>(s6, 128, 128L * MNODE, x34, 256, 512L * MNODE,
                                                     c7w, 384, nullptr, bn7cs, bn7cb, 1,
                                                     s7, 128L * MNODE, 128, MNODE);
    // unpool
    k_knn3<<<dim3(1024), dim3(256), 0, stream>>>(x, node, k3i, k3w);
    k_unpool<<<dim3(16384), dim3(256), 0, stream>>>(s7, k3i, k3w, sup);
    // conv8 / conv9 / conv10 (8-wide o-tile, R10 config)
    k_conv<<<dim3(8, 16, 4), dim3(256), 0, stream>>>(sup, 128, 128L * NPTS, xt1 + 64L * NPTS, 64,
                                                     128L * NPTS, c8w, 192, nullptr, bn8s, bn8b, 1,
                                                     s8, 128L * NPTS, 128, NPTS);
    k_conv<<<dim3(8, 16, 4), dim3(256), 0, stream>>>(s8, 128, 128L * NPTS, xt1, 64, 128L * NPTS,
                                                     c9w, 192, nullptr, bn9s, bn9b, 1,
                                                     s9, 128L * NPTS, 128, NPTS);
    k_conv<<<dim3(8, 1, 4), dim3(256), 0, stream>>>(s9, 128, 128L * NPTS, nullptr, 0, 0,
                                                    c10w, 128, nullptr, nullptr, nullptr, 0,
                                                    out_seg, 2L * NPTS, 2, NPTS);
    (void)in_sizes; (void)n_in; (void)out_size; (void)ws_size;
}